// Round 4
// baseline (840.504 us; speedup 1.0000x reference)
//
#include <hip/hip_runtime.h>
#include <stdint.h>

// ---- problem constants (MistralAttention: B=2,S=2048,H=32,KVH=8,D=128) ----
#define NH      32
#define NKVH    8
#define HD      128
#define BATCH   2
#define SEQ     2048
#define HIDDEN  4096
#define KVDIM   1024
#define TOKENS  (BATCH*SEQ)

typedef __bf16 bf16x8 __attribute__((ext_vector_type(8)));
typedef float  f32x4  __attribute__((ext_vector_type(4)));

__device__ __forceinline__ uint16_t f32_to_bf16(float f) {
  union { float f; uint32_t u; } v; v.f = f;
  uint32_t r = v.u + 0x7FFFu + ((v.u >> 16) & 1u);   // RNE
  return (uint16_t)(r >> 16);
}
__device__ __forceinline__ float bf16_to_f32(uint16_t h) {
  union { uint32_t u; float f; } v; v.u = ((uint32_t)h) << 16;
  return v.f;
}
__device__ __forceinline__ bf16x8 ld_frag(const uint16_t* p) {
  return *(const bf16x8*)p;
}
#define MFMA_BF16(a,b,c) __builtin_amdgcn_mfma_f32_16x16x32_bf16((a),(b),(c),0,0,0)
#define NEG_BIG (-1.0e30f)

typedef __attribute__((address_space(1))) void as1_void;
typedef __attribute__((address_space(3))) void as3_void;
// async global->LDS, 16B per lane; LDS dest = wave-uniform base + lane*16
__device__ __forceinline__ void gload_lds16(const void* g, void* l) {
  __builtin_amdgcn_global_load_lds((as1_void*)g, (as3_void*)l, 16, 0, 0);
}

// ============================================================================
// fp32 -> bf16 conversion; single kernel for X, Wq, Wk, Wv (exact grids)
// ============================================================================
__device__ __forceinline__ void cvt8(const float* __restrict__ s,
                                     uint16_t* __restrict__ d, size_t i) {
  const float4* sp = (const float4*)s + 2*i;
  float4 a = sp[0], b = sp[1];
  union { uint16_t u[8]; uint4 v; } o;
  o.u[0]=f32_to_bf16(a.x); o.u[1]=f32_to_bf16(a.y);
  o.u[2]=f32_to_bf16(a.z); o.u[3]=f32_to_bf16(a.w);
  o.u[4]=f32_to_bf16(b.x); o.u[5]=f32_to_bf16(b.y);
  o.u[6]=f32_to_bf16(b.z); o.u[7]=f32_to_bf16(b.w);
  ((uint4*)d)[i] = o.v;
}

// grid.x = 8192 + 8192 + 2048 + 2048 = 20480 blocks of 256 (exact, no tails)
__global__ __launch_bounds__(256) void cvt_all(
    const float* __restrict__ X,  const float* __restrict__ Wq,
    const float* __restrict__ Wk, const float* __restrict__ Wv,
    uint16_t* __restrict__ R0, uint16_t* __restrict__ R1,
    uint16_t* __restrict__ R2, uint16_t* __restrict__ R3)
{
  int blk = blockIdx.x;
  const float* s; uint16_t* d; int b0;
  if (blk < 8192)       { s = X;  d = R0; b0 = 0; }
  else if (blk < 16384) { s = Wq; d = R1; b0 = 8192; }
  else if (blk < 18432) { s = Wk; d = R2; b0 = 16384; }
  else                  { s = Wv; d = R3; b0 = 18432; }
  cvt8(s, d, (size_t)(blk - b0)*256 + threadIdx.x);
}

__global__ __launch_bounds__(256) void cvt_one(
    const float* __restrict__ s, uint16_t* __restrict__ d)
{
  cvt8(s, d, (size_t)blockIdx.x*256 + threadIdx.x);
}

// ============================================================================
// GEMM engine v4: v3 ring (m97 geometry, 3-slot LDS ring, counted vmcnt(4))
//   + T2 bank-conflict swizzle on the fragment path.
//   Swizzle: within each 64B row, physical 16B slot = logical_slot ^ ((row>>1)&3).
//   - staging keeps LINEAR global_load_lds dest; the per-lane GLOBAL source
//     column is pre-swizzled (rule #21: linear dest + inverse-swz source).
//     staged row bits[2:1] = (lane>>3)&3  ->  scol = ((lane&3)^((lane>>3)&3))*8
//   - ds_read fragment offset swizzled:   read row bits[2:1] = (fr>>1)&3
//     ->  fo = ((lane>>4) ^ ((fr>>1)&3)) * 8   (lane-constant, zero per-iter cost)
//   Effect: 16-lane read phase start-banks 16*(row&1)+4*slot now 2-per-group
//   (free, m136) instead of 8-way (2.94x).
// ============================================================================
__device__ __forceinline__ void store_c(uint16_t* p, float v) { *p = f32_to_bf16(v); }
__device__ __forceinline__ void store_c(float*    p, float v) { *p = v; }

template <typename TC>
__device__ __forceinline__ void gemm_body(
    const uint16_t* __restrict__ A, const uint16_t* __restrict__ B,
    TC* __restrict__ C, int m0, int n0, int N, int K)
{
  __shared__ __align__(16) uint16_t As[3][128*32];
  __shared__ __align__(16) uint16_t Bs[3][128*32];
  const int tid  = threadIdx.x;
  const int wave = tid >> 6;
  const int lane = tid & 63;
  const int wm = (wave >> 1) * 64;
  const int wn = (wave & 1) * 64;
  const int srow = lane >> 2;          // staging: 4 lanes x 16B per 64B row
  const int scol = (((lane & 3) ^ ((lane >> 3) & 3)) * 8);   // swizzled source
  const uint16_t* Ap = A + (size_t)(m0 + wave*16 + srow) * K + scol;
  const uint16_t* Bp = B + (size_t)(n0 + wave*16 + srow) * K + scol;
  const int wuo = wave*16*32;          // wave-uniform strip offset (elements)
  const int fr = lane & 15;
  const int fo = (((lane >> 4) ^ ((fr >> 1) & 3)) * 8);      // swizzled read
  const int NT = K / 32;

  // prologue: stage tiles 0 and 1 into slots 0 and 1
  #pragma unroll
  for (int t = 0; t < 2; ++t) {
    gload_lds16(Ap + (size_t)t*32,                &As[t][wuo]);
    gload_lds16(Ap + (size_t)64*K + (size_t)t*32, &As[t][64*32 + wuo]);
    gload_lds16(Bp + (size_t)t*32,                &Bs[t][wuo]);
    gload_lds16(Bp + (size_t)64*K + (size_t)t*32, &Bs[t][64*32 + wuo]);
  }

  f32x4 acc[4][4] = {};
  int s_cur = 0, s_stage = 2;          // slot of tile t; slot for tile t+2
  for (int t = 0; t < NT; ++t) {
    // retire exactly tile t's 4 loads; keep tile t+1's 4 in flight
    if (t < NT - 1) asm volatile("s_waitcnt vmcnt(4)" ::: "memory");
    else            asm volatile("s_waitcnt vmcnt(0)" ::: "memory");
    __builtin_amdgcn_s_barrier();
    asm volatile("" ::: "memory");

    // stage tile t+2 into the slot tile t-1 occupied (dead past the barrier)
    if (t + 2 < NT) {
      const size_t k2 = (size_t)(t + 2) * 32;
      gload_lds16(Ap + k2,                &As[s_stage][wuo]);
      gload_lds16(Ap + (size_t)64*K + k2, &As[s_stage][64*32 + wuo]);
      gload_lds16(Bp + k2,                &Bs[s_stage][wuo]);
      gload_lds16(Bp + (size_t)64*K + k2, &Bs[s_stage][64*32 + wuo]);
    }

    const uint16_t* Asb = As[s_cur];
    const uint16_t* Bsb = Bs[s_cur];
    bf16x8 af[4], bfr[4];
    #pragma unroll
    for (int i = 0; i < 4; ++i) af[i]  = ld_frag(&Asb[(wm + i*16 + fr)*32 + fo]);
    #pragma unroll
    for (int j = 0; j < 4; ++j) bfr[j] = ld_frag(&Bsb[(wn + j*16 + fr)*32 + fo]);
    __builtin_amdgcn_s_setprio(1);
    #pragma unroll
    for (int i = 0; i < 4; ++i)
      #pragma unroll
      for (int j = 0; j < 4; ++j)
        acc[i][j] = MFMA_BF16(af[i], bfr[j], acc[i][j]);
    __builtin_amdgcn_s_setprio(0);

    s_cur   = (s_cur   == 2) ? 0 : s_cur + 1;
    s_stage = (s_stage == 2) ? 0 : s_stage + 1;
  }

  const int cr = (lane >> 4) * 4;      // C layout: col=lane&15, row=(lane>>4)*4+reg
  const int cfr = lane & 15;
  #pragma unroll
  for (int i = 0; i < 4; ++i)
    #pragma unroll
    for (int j = 0; j < 4; ++j)
      #pragma unroll
      for (int r = 0; r < 4; ++r)
        store_c(&C[(size_t)(m0 + wm + i*16 + cr + r) * N + (n0 + wn + j*16 + cfr)],
                acc[i][j][r]);
}

// fused Q/K/V projection: grid.x = 32 (Q) + 8 (K) + 8 (V); grid 48x32=1536
// = exactly 2 full device rounds at 3 blocks/CU
__global__ __launch_bounds__(256, 3) void qkv_gemm(
    const uint16_t* __restrict__ X,
    const uint16_t* __restrict__ Wq, const uint16_t* __restrict__ Wk,
    const uint16_t* __restrict__ Wv,
    uint16_t* __restrict__ Qo, uint16_t* __restrict__ Ko, uint16_t* __restrict__ Vo)
{
  int bx = blockIdx.x;
  const uint16_t* B; uint16_t* C; int n0, N;
  if (bx < 32)      { B = Wq; C = Qo; n0 = bx*128;      N = HIDDEN; }
  else if (bx < 40) { B = Wk; C = Ko; n0 = (bx-32)*128; N = KVDIM;  }
  else              { B = Wv; C = Vo; n0 = (bx-40)*128; N = KVDIM;  }
  gemm_body<uint16_t>(X, B, C, blockIdx.y*128, n0, N, HIDDEN);
}

// final projection: C fp32 to d_out
__global__ __launch_bounds__(256, 3) void out_gemm(
    const uint16_t* __restrict__ A, const uint16_t* __restrict__ B,
    float* __restrict__ C, int N, int K)
{
  gemm_body<float>(A, B, C, blockIdx.y*128, blockIdx.x*128, N, K);
}

// ============================================================================
// RoPE in-place on Q [TOKENS,HIDDEN] and K [TOKENS,KVDIM] (bf16)
// position = (t % SEQ); inv_freq = 10000^(-j/64) = 10^(-j/16)
// ============================================================================
__global__ __launch_bounds__(256) void rope_kernel(
    uint16_t* __restrict__ Q, uint16_t* __restrict__ K)
{
  int idx = blockIdx.x * 256 + threadIdx.x;
  int j = idx & 63;
  int rest = idx >> 6;
  int h = rest % (NH + NKVH);
  int t = rest / (NH + NKVH);
  float pos = (float)(t % SEQ);
  float inv_freq = __exp10f(-0.0625f * (float)j);
  float ang = pos * inv_freq;
  float s, c;
  __sincosf(ang, &s, &c);
  uint16_t* base = (h < NH) ? (Q + (size_t)t*HIDDEN + h*HD)
                            : (K + (size_t)t*KVDIM + (h-NH)*HD);
  float x1 = bf16_to_f32(base[j]);
  float x2 = bf16_to_f32(base[j+64]);
  base[j]    = f32_to_bf16(x1*c - x2*s);
  base[j+64] = f32_to_bf16(x2*c + x1*s);
}

// ============================================================================
// V transpose: V[TOKENS,KVDIM](bf16) -> Vt[B][KVH][HD][SEQ](bf16)
// ============================================================================
__global__ __launch_bounds__(256) void transpose_v(
    const uint16_t* __restrict__ V, uint16_t* __restrict__ Vt)
{
  __shared__ uint16_t tile[64][66];
  int bh = blockIdx.z;  int b = bh >> 3, h = bh & 7;
  int s0 = blockIdx.x * 64;
  int d0 = blockIdx.y * 64;
  int tx = threadIdx.x & 63;
  int ty = threadIdx.x >> 6;
  const uint16_t* Vp = V + (size_t)b*SEQ*KVDIM + (size_t)h*HD;
  for (int r = ty; r < 64; r += 4)
    tile[r][tx] = Vp[(size_t)(s0 + r)*KVDIM + d0 + tx];
  __syncthreads();
  uint16_t* Vtp = Vt + ((size_t)b*NKVH + h)*HD*SEQ;
  for (int r = ty; r < 64; r += 4)
    Vtp[(size_t)(d0 + r)*SEQ + s0 + tx] = tile[tx][r];
}

// ============================================================================
// Flash attention (causal, GQA), occupancy-optimized:
//  - BQ=64 (each of 4 waves owns 16 q-rows) -> low VGPR -> 4 waves/SIMD
//  - Ps aliased into Ks (dead after QK^T) -> 35.8 KB LDS -> 4 blocks/CU
//  - q-tile pairing (bx, 31-bx): every block runs exactly 33 k-iterations
//  - 3 syncthreads per 64-key tile; PV reads only the wave's own Ps strip
//  - O written in-place over Q (each Q row is read only by its owning block)
// ============================================================================
#define KSTR 136   // Ks row stride (128 cols + 8 pad)
#define VSTR 72    // Vs/Ps row stride (64 cols + 8 pad)

__global__ __launch_bounds__(256, 4) void flash_attn(
    uint16_t* __restrict__ Q, const uint16_t* __restrict__ K,
    const uint16_t* __restrict__ Vt)
{
  __shared__ __align__(16) uint16_t Ks[64*KSTR];    // 17.0 KB (Ps aliases this)
  __shared__ __align__(16) uint16_t Vs[128*VSTR];   // 18.0 KB
  uint16_t* Ps = Ks;  // [q=64][key=64] stride VSTR — fits in Ks region

  const int tid  = threadIdx.x;
  const int wave = tid >> 6;
  const int lane = tid & 63;
  const int fr = lane & 15;
  const int g  = lane >> 4;
  const int fo = g * 8;
  const int bh = blockIdx.y;
  const int b = bh >> 5, h = bh & 31;
  const int kvh = h >> 2;   // GQA: 4 Q-heads per KV-head

  uint16_t*       Qh = Q  + (size_t)b*SEQ*HIDDEN + (size_t)h*HD;
  const uint16_t* Kp = K  + (size_t)b*SEQ*KVDIM  + (size_t)kvh*HD;
  const uint16_t* Vp = Vt + ((size_t)b*NKVH + kvh)*HD*SEQ;

  #pragma unroll
  for (int pass = 0; pass < 2; ++pass) {
    const int qt = pass ? (31 - (int)blockIdx.x) : (int)blockIdx.x;
    const int q0 = qt * 64;
    const int qrow_base = q0 + wave*16 + g*4;   // + r = this lane's softmax rows

    // Q fragments (A-layout): wave's 16 q-rows, d=0..127
    bf16x8 qf[4];
    #pragma unroll
    for (int ks = 0; ks < 4; ++ks)
      qf[ks] = ld_frag(Qh + (size_t)(q0 + wave*16 + fr)*HIDDEN + ks*32 + fo);

    float m_i[4], l_i[4];
    f32x4 oacc[8] = {};
    #pragma unroll
    for (int r = 0; r < 4; ++r) { m_i[r] = NEG_BIG; l_i[r] = 0.f; }

    const int nkt = qt + 1;   // causal: keys up to q0+63
    for (int kt = 0; kt < nkt; ++kt) {
      const int k0 = kt * 64;
      __syncthreads();   // prev iter's Vs/Ps reads done before restaging
      #pragma unroll
      for (int i = 0; i < 4; ++i) {
        int gi = tid + i*256;                    // 0..1023
        int kr = gi >> 4, kc = (gi & 15) * 8;    // Ks: 64 x 128
        *(bf16x8*)&Ks[kr*KSTR + kc] = *(const bf16x8*)(Kp + (size_t)(k0 + kr)*KVDIM + kc);
        int vr = gi >> 3, vc = (gi & 7) * 8;     // Vs: 128 x 64
        *(bf16x8*)&Vs[vr*VSTR + vc] = *(const bf16x8*)(Vp + (size_t)vr*SEQ + k0 + vc);
      }
      __syncthreads();

      // S = Q K^T   (16 q-rows x 64 keys per wave)
      f32x4 sacc[4] = {};
      #pragma unroll
      for (int ks = 0; ks < 4; ++ks) {
        bf16x8 bk[4];
        #pragma unroll
        for (int j = 0; j < 4; ++j) bk[j] = ld_frag(&Ks[(j*16 + fr)*KSTR + ks*32 + fo]);
        #pragma unroll
        for (int j = 0; j < 4; ++j) sacc[j] = MFMA_BF16(qf[ks], bk[j], sacc[j]);
      }

      // scale + causal mask + online softmax (row spans 16 lanes of this g-group)
      const bool diag = (kt == qt);
      #pragma unroll
      for (int r = 0; r < 4; ++r) {
        float vals[4];
        #pragma unroll
        for (int j = 0; j < 4; ++j) {
          float v = sacc[j][r] * 0.08838834764831845f;  // 1/sqrt(128)
          if (diag && (k0 + j*16 + fr > qrow_base + r)) v = NEG_BIG;
          vals[j] = v;
        }
        float mt = fmaxf(fmaxf(vals[0], vals[1]), fmaxf(vals[2], vals[3]));
        #pragma unroll
        for (int off = 1; off < 16; off <<= 1) mt = fmaxf(mt, __shfl_xor(mt, off, 64));
        float mn = fmaxf(m_i[r], mt);
        float alpha = __expf(fminf(m_i[r] - mn, 0.f));
        float lt = 0.f;
        #pragma unroll
        for (int j = 0; j < 4; ++j) {
          float p = __expf(fminf(vals[j] - mn, 0.f));
          sacc[j][r] = p;
          lt += p;
        }
        #pragma unroll
        for (int off = 1; off < 16; off <<= 1) lt += __shfl_xor(lt, off, 64);
        m_i[r] = mn;
        l_i[r] = l_i[r]*alpha + lt;
        #pragma unroll
        for (int n = 0; n < 8; ++n) oacc[n][r] *= alpha;
      }

      __syncthreads();   // all waves finished reading Ks before P overwrites it

      // P (C-layout) -> Ps (A-layout source); wave writes/reads only its strip
      #pragma unroll
      for (int j = 0; j < 4; ++j)
        #pragma unroll
        for (int r = 0; r < 4; ++r)
          Ps[(wave*16 + g*4 + r)*VSTR + j*16 + fr] = f32_to_bf16(sacc[j][r]);

      // O += P * V   (no barrier: own-strip Ps; Vs stable since staging)
      #pragma unroll
      for (int ks = 0; ks < 2; ++ks) {
        bf16x8 ap = ld_frag(&Ps[(wave*16 + fr)*VSTR + ks*32 + fo]);
        #pragma unroll
        for (int half = 0; half < 2; ++half) {
          bf16x8 bv[4];
          #pragma unroll
          for (int n = 0; n < 4; ++n)
            bv[n] = ld_frag(&Vs[((half*4 + n)*16 + fr)*VSTR + ks*32 + fo]);
          #pragma unroll
          for (int n = 0; n < 4; ++n)
            oacc[half*4 + n] = MFMA_BF16(ap, bv[n], oacc[half*4 + n]);
        }
      }
    }

    // epilogue: O over Q in-place (only this block's rows)
    #pragma unroll
    for (int r = 0; r < 4; ++r) {
      float inv_l = 1.0f / l_i[r];
      #pragma unroll
      for (int n = 0; n < 8; ++n)
        Qh[(size_t)(qrow_base + r)*HIDDEN + n*16 + fr] = f32_to_bf16(oacc[n][r] * inv_l);
    }
    __syncthreads();   // LDS/Q safe before next pass
  }
}

// ============================================================================
extern "C" void kernel_launch(void* const* d_in, const int* in_sizes, int n_in,
                              void* d_out, int out_size, void* d_ws, size_t ws_size,
                              hipStream_t stream)
{
  (void)in_sizes; (void)n_in; (void)out_size; (void)ws_size;
  const float* hidden = (const float*)d_in[0];   // fp32 per reference
  const float* wq = (const float*)d_in[2];
  const float* wk = (const float*)d_in[3];
  const float* wv = (const float*)d_in[4];
  const float* wo = (const float*)d_in[5];
  float* out = (float*)d_out;                    // fp32 per reference output

  // bf16 workspace with aliasing (~134 MB):
  //  R0: Xb (until qkv) -> Wob ; R1: Wqb (until qkv) -> Vt
  uint16_t* R0 = (uint16_t*)d_ws;                         // 16.78M elems
  uint16_t* R1 = R0 + (size_t)HIDDEN*HIDDEN;              // 16.78M
  uint16_t* R2 = R1 + (size_t)HIDDEN*HIDDEN;              //  4.19M
  uint16_t* R3 = R2 + (size_t)KVDIM*HIDDEN;               //  4.19M
  uint16_t* Qb = R3 + (size_t)KVDIM*HIDDEN;               // 16.78M
  uint16_t* Kb = Qb + (size_t)TOKENS*HIDDEN;              //  4.19M
  uint16_t* Vb = Kb + (size_t)TOKENS*KVDIM;               //  4.19M

  dim3 blk(256);
  cvt_all<<<dim3(20480), blk, 0, stream>>>(hidden, wq, wk, wv, R0, R1, R2, R3);
  qkv_gemm<<<dim3(48, TOKENS/128), blk, 0, stream>>>(R0, R1, R2, R3, Qb, Kb, Vb);
  rope_kernel<<<dim3(TOKENS*(NH+NKVH)*64/256), blk, 0, stream>>>(Qb, Kb);
  cvt_one<<<dim3(HIDDEN*HIDDEN/8/256), blk, 0, stream>>>(wo, R0);   // Wo -> R0 (Xb dead)
  transpose_v<<<dim3(SEQ/64, HD/64, BATCH*NKVH), blk, 0, stream>>>(Vb, R1); // Vt -> R1
  flash_attn<<<dim3(16, BATCH*NH), blk, 0, stream>>>(Qb, Kb, R1);
  out_gemm<<<dim3(HIDDEN/128, TOKENS/128), blk, 0, stream>>>(Qb, R0, out, HIDDEN, HIDDEN);
}

// Round 10
// 802.037 us; speedup vs baseline: 1.0480x; 1.0480x over previous
//
#include <hip/hip_runtime.h>
#include <stdint.h>

// ---- problem constants (MistralAttention: B=2,S=2048,H=32,KVH=8,D=128) ----
#define NH      32
#define NKVH    8
#define HD      128
#define BATCH   2
#define SEQ     2048
#define HIDDEN  4096
#define KVDIM   1024
#define TOKENS  (BATCH*SEQ)

typedef __bf16 bf16x8 __attribute__((ext_vector_type(8)));
typedef float  f32x4  __attribute__((ext_vector_type(4)));

__device__ __forceinline__ uint16_t f32_to_bf16(float f) {
  union { float f; uint32_t u; } v; v.f = f;
  uint32_t r = v.u + 0x7FFFu + ((v.u >> 16) & 1u);   // RNE
  return (uint16_t)(r >> 16);
}
__device__ __forceinline__ float bf16_to_f32(uint16_t h) {
  union { uint32_t u; float f; } v; v.u = ((uint32_t)h) << 16;
  return v.f;
}
__device__ __forceinline__ bf16x8 ld_frag(const uint16_t* p) {
  return *(const bf16x8*)p;
}
#define MFMA_BF16(a,b,c) __builtin_amdgcn_mfma_f32_16x16x32_bf16((a),(b),(c),0,0,0)
#define NEG_BIG (-1.0e30f)

typedef __attribute__((address_space(1))) void as1_void;
typedef __attribute__((address_space(3))) void as3_void;
// async global->LDS, 16B per lane; LDS dest = wave-uniform base + lane*16
__device__ __forceinline__ void gload_lds16(const void* g, void* l) {
  __builtin_amdgcn_global_load_lds((as1_void*)g, (as3_void*)l, 16, 0, 0);
}

// ============================================================================
// fp32 -> bf16 conversion; single kernel for X, Wq, Wk, Wv (exact grids)
// ============================================================================
__device__ __forceinline__ void cvt8(const float* __restrict__ s,
                                     uint16_t* __restrict__ d, size_t i) {
  const float4* sp = (const float4*)s + 2*i;
  float4 a = sp[0], b = sp[1];
  union { uint16_t u[8]; uint4 v; } o;
  o.u[0]=f32_to_bf16(a.x); o.u[1]=f32_to_bf16(a.y);
  o.u[2]=f32_to_bf16(a.z); o.u[3]=f32_to_bf16(a.w);
  o.u[4]=f32_to_bf16(b.x); o.u[5]=f32_to_bf16(b.y);
  o.u[6]=f32_to_bf16(b.z); o.u[7]=f32_to_bf16(b.w);
  ((uint4*)d)[i] = o.v;
}

// grid.x = 8192 + 8192 + 2048 + 2048 = 20480 blocks of 256 (exact, no tails)
__global__ __launch_bounds__(256) void cvt_all(
    const float* __restrict__ X,  const float* __restrict__ Wq,
    const float* __restrict__ Wk, const float* __restrict__ Wv,
    uint16_t* __restrict__ R0, uint16_t* __restrict__ R1,
    uint16_t* __restrict__ R2, uint16_t* __restrict__ R3)
{
  int blk = blockIdx.x;
  const float* s; uint16_t* d; int b0;
  if (blk < 8192)       { s = X;  d = R0; b0 = 0; }
  else if (blk < 16384) { s = Wq; d = R1; b0 = 8192; }
  else if (blk < 18432) { s = Wk; d = R2; b0 = 16384; }
  else                  { s = Wv; d = R3; b0 = 18432; }
  cvt8(s, d, (size_t)(blk - b0)*256 + threadIdx.x);
}

__global__ __launch_bounds__(256) void cvt_one(
    const float* __restrict__ s, uint16_t* __restrict__ d)
{
  cvt8(s, d, (size_t)blockIdx.x*256 + threadIdx.x);
}

// ============================================================================
// GEMM engine v4: m97 geometry + 3-slot ring + counted vmcnt(4) + T2 swizzle
// (bank conflicts measured 0; timing-neutral but free — kept)
// ============================================================================
__device__ __forceinline__ void store_c(uint16_t* p, float v) { *p = f32_to_bf16(v); }
__device__ __forceinline__ void store_c(float*    p, float v) { *p = v; }

template <typename TC>
__device__ __forceinline__ void gemm_body(
    const uint16_t* __restrict__ A, const uint16_t* __restrict__ B,
    TC* __restrict__ C, int m0, int n0, int N, int K)
{
  __shared__ __align__(16) uint16_t As[3][128*32];
  __shared__ __align__(16) uint16_t Bs[3][128*32];
  const int tid  = threadIdx.x;
  const int wave = tid >> 6;
  const int lane = tid & 63;
  const int wm = (wave >> 1) * 64;
  const int wn = (wave & 1) * 64;
  const int srow = lane >> 2;          // staging: 4 lanes x 16B per 64B row
  const int scol = (((lane & 3) ^ ((lane >> 3) & 3)) * 8);   // swizzled source
  const uint16_t* Ap = A + (size_t)(m0 + wave*16 + srow) * K + scol;
  const uint16_t* Bp = B + (size_t)(n0 + wave*16 + srow) * K + scol;
  const int wuo = wave*16*32;          // wave-uniform strip offset (elements)
  const int fr = lane & 15;
  const int fo = (((lane >> 4) ^ ((fr >> 1) & 3)) * 8);      // swizzled read
  const int NT = K / 32;

  // prologue: stage tiles 0 and 1 into slots 0 and 1
  #pragma unroll
  for (int t = 0; t < 2; ++t) {
    gload_lds16(Ap + (size_t)t*32,                &As[t][wuo]);
    gload_lds16(Ap + (size_t)64*K + (size_t)t*32, &As[t][64*32 + wuo]);
    gload_lds16(Bp + (size_t)t*32,                &Bs[t][wuo]);
    gload_lds16(Bp + (size_t)64*K + (size_t)t*32, &Bs[t][64*32 + wuo]);
  }

  f32x4 acc[4][4] = {};
  int s_cur = 0, s_stage = 2;          // slot of tile t; slot for tile t+2
  for (int t = 0; t < NT; ++t) {
    // retire exactly tile t's 4 loads; keep tile t+1's 4 in flight
    if (t < NT - 1) asm volatile("s_waitcnt vmcnt(4)" ::: "memory");
    else            asm volatile("s_waitcnt vmcnt(0)" ::: "memory");
    __builtin_amdgcn_s_barrier();
    asm volatile("" ::: "memory");

    // stage tile t+2 into the slot tile t-1 occupied (dead past the barrier)
    if (t + 2 < NT) {
      const size_t k2 = (size_t)(t + 2) * 32;
      gload_lds16(Ap + k2,                &As[s_stage][wuo]);
      gload_lds16(Ap + (size_t)64*K + k2, &As[s_stage][64*32 + wuo]);
      gload_lds16(Bp + k2,                &Bs[s_stage][wuo]);
      gload_lds16(Bp + (size_t)64*K + k2, &Bs[s_stage][64*32 + wuo]);
    }

    const uint16_t* Asb = As[s_cur];
    const uint16_t* Bsb = Bs[s_cur];
    bf16x8 af[4], bfr[4];
    #pragma unroll
    for (int i = 0; i < 4; ++i) af[i]  = ld_frag(&Asb[(wm + i*16 + fr)*32 + fo]);
    #pragma unroll
    for (int j = 0; j < 4; ++j) bfr[j] = ld_frag(&Bsb[(wn + j*16 + fr)*32 + fo]);
    __builtin_amdgcn_s_setprio(1);
    #pragma unroll
    for (int i = 0; i < 4; ++i)
      #pragma unroll
      for (int j = 0; j < 4; ++j)
        acc[i][j] = MFMA_BF16(af[i], bfr[j], acc[i][j]);
    __builtin_amdgcn_s_setprio(0);

    s_cur   = (s_cur   == 2) ? 0 : s_cur + 1;
    s_stage = (s_stage == 2) ? 0 : s_stage + 1;
  }

  const int cr = (lane >> 4) * 4;      // C layout: col=lane&15, row=(lane>>4)*4+reg
  const int cfr = lane & 15;
  #pragma unroll
  for (int i = 0; i < 4; ++i)
    #pragma unroll
    for (int j = 0; j < 4; ++j)
      #pragma unroll
      for (int r = 0; r < 4; ++r)
        store_c(&C[(size_t)(m0 + wm + i*16 + cr + r) * N + (n0 + wn + j*16 + cfr)],
                acc[i][j][r]);
}

// fused Q/K/V projection: grid.x = 32 (Q) + 8 (K) + 8 (V); grid 48x32=1536
__global__ __launch_bounds__(256, 3) void qkv_gemm(
    const uint16_t* __restrict__ X,
    const uint16_t* __restrict__ Wq, const uint16_t* __restrict__ Wk,
    const uint16_t* __restrict__ Wv,
    uint16_t* __restrict__ Qo, uint16_t* __restrict__ Ko, uint16_t* __restrict__ Vo)
{
  int bx = blockIdx.x;
  const uint16_t* B; uint16_t* C; int n0, N;
  if (bx < 32)      { B = Wq; C = Qo; n0 = bx*128;      N = HIDDEN; }
  else if (bx < 40) { B = Wk; C = Ko; n0 = (bx-32)*128; N = KVDIM;  }
  else              { B = Wv; C = Vo; n0 = (bx-40)*128; N = KVDIM;  }
  gemm_body<uint16_t>(X, B, C, blockIdx.y*128, n0, N, HIDDEN);
}

// final projection: C fp32 to d_out
__global__ __launch_bounds__(256, 3) void out_gemm(
    const uint16_t* __restrict__ A, const uint16_t* __restrict__ B,
    float* __restrict__ C, int N, int K)
{
  gemm_body<float>(A, B, C, blockIdx.y*128, blockIdx.x*128, N, K);
}

// ============================================================================
// RoPE in-place on Q [TOKENS,HIDDEN] and K [TOKENS,KVDIM] (bf16)
// ============================================================================
__global__ __launch_bounds__(256) void rope_kernel(
    uint16_t* __restrict__ Q, uint16_t* __restrict__ K)
{
  int idx = blockIdx.x * 256 + threadIdx.x;
  int j = idx & 63;
  int rest = idx >> 6;
  int h = rest % (NH + NKVH);
  int t = rest / (NH + NKVH);
  float pos = (float)(t % SEQ);
  float inv_freq = __exp10f(-0.0625f * (float)j);
  float ang = pos * inv_freq;
  float s, c;
  __sincosf(ang, &s, &c);
  uint16_t* base = (h < NH) ? (Q + (size_t)t*HIDDEN + h*HD)
                            : (K + (size_t)t*KVDIM + (h-NH)*HD);
  float x1 = bf16_to_f32(base[j]);
  float x2 = bf16_to_f32(base[j+64]);
  base[j]    = f32_to_bf16(x1*c - x2*s);
  base[j+64] = f32_to_bf16(x2*c + x1*s);
}

// ============================================================================
// V transpose: V[TOKENS,KVDIM](bf16) -> Vt[B][KVH][HD][SEQ](bf16)
// ============================================================================
__global__ __launch_bounds__(256) void transpose_v(
    const uint16_t* __restrict__ V, uint16_t* __restrict__ Vt)
{
  __shared__ uint16_t tile[64][66];
  int bh = blockIdx.z;  int b = bh >> 3, h = bh & 7;
  int s0 = blockIdx.x * 64;
  int d0 = blockIdx.y * 64;
  int tx = threadIdx.x & 63;
  int ty = threadIdx.x >> 6;
  const uint16_t* Vp = V + (size_t)b*SEQ*KVDIM + (size_t)h*HD;
  for (int r = ty; r < 64; r += 4)
    tile[r][tx] = Vp[(size_t)(s0 + r)*KVDIM + d0 + tx];
  __syncthreads();
  uint16_t* Vtp = Vt + ((size_t)b*NKVH + h)*HD*SEQ;
  for (int r = ty; r < 64; r += 4)
    Vtp[(size_t)(d0 + r)*SEQ + s0 + tx] = tile[tx][r];
}

// ============================================================================
// Flash attention v2 (causal, GQA): SWAPPED QK^T softmax.
//  - S^T = mfma(K, Q): C layout => q = lane&15 (LANE-LOCAL row),
//    key = j*16 + g*4 + r. Each lane owns 16 P-values of ONE q-row.
//    Row-reduce: 15 local fmax/add + 2 cross-group shfl (was 16 shfl).
//  - T13 defer-max: skip O-rescale when __all(mt <= m_i + 8) (THR=8, m239).
//  - P->Ps: 4 x ds_write_b64 packed (was 16 x ds_write_b16).
//  - alpha / l broadcast fr-space -> (g*4+r)-space via __shfl (rescale path
//    and epilogue only).
//  - T5 setprio around MFMA clusters (m191: +4-7% attn).
//  Everything else (staging, PV, aliasing, pairing) unchanged from v1.
// ============================================================================
#define KSTR 136   // Ks row stride (128 cols + 8 pad)
#define VSTR 72    // Vs/Ps row stride (64 cols + 8 pad)

__global__ __launch_bounds__(256, 4) void flash_attn(
    uint16_t* __restrict__ Q, const uint16_t* __restrict__ K,
    const uint16_t* __restrict__ Vt)
{
  __shared__ __align__(16) uint16_t Ks[64*KSTR];    // 17.0 KB (Ps aliases this)
  __shared__ __align__(16) uint16_t Vs[128*VSTR];   // 18.0 KB
  uint16_t* Ps = Ks;  // [q=64][key=64] stride VSTR — fits in Ks region

  const int tid  = threadIdx.x;
  const int wave = tid >> 6;
  const int lane = tid & 63;
  const int fr = lane & 15;
  const int g  = lane >> 4;
  const int fo = g * 8;
  const int bh = blockIdx.y;
  const int b = bh >> 5, h = bh & 31;
  const int kvh = h >> 2;   // GQA: 4 Q-heads per KV-head

  uint16_t*       Qh = Q  + (size_t)b*SEQ*HIDDEN + (size_t)h*HD;
  const uint16_t* Kp = K  + (size_t)b*SEQ*KVDIM  + (size_t)kvh*HD;
  const uint16_t* Vp = Vt + ((size_t)b*NKVH + kvh)*HD*SEQ;

  #pragma unroll
  for (int pass = 0; pass < 2; ++pass) {
    const int qt = pass ? (31 - (int)blockIdx.x) : (int)blockIdx.x;
    const int q0 = qt * 64;
    const int qrow = q0 + wave*16 + fr;         // this lane's softmax q-row
    const int orow_base = q0 + wave*16 + g*4;   // + r = this lane's O rows

    // Q fragments: wave's 16 q-rows (row = fr), d=0..127
    bf16x8 qf[4];
    #pragma unroll
    for (int ks = 0; ks < 4; ++ks)
      qf[ks] = ld_frag(Qh + (size_t)(q0 + wave*16 + fr)*HIDDEN + ks*32 + fo);

    float m_i = NEG_BIG, l_i = 0.f;
    f32x4 oacc[8] = {};

    const int nkt = qt + 1;   // causal: keys up to q0+63
    for (int kt = 0; kt < nkt; ++kt) {
      const int k0 = kt * 64;
      __syncthreads();   // prev iter's Vs/Ps reads done before restaging
      #pragma unroll
      for (int i = 0; i < 4; ++i) {
        int gi = tid + i*256;                    // 0..1023
        int kr = gi >> 4, kc = (gi & 15) * 8;    // Ks: 64 x 128
        *(bf16x8*)&Ks[kr*KSTR + kc] = *(const bf16x8*)(Kp + (size_t)(k0 + kr)*KVDIM + kc);
        int vr = gi >> 3, vc = (gi & 7) * 8;     // Vs: 128 x 64
        *(bf16x8*)&Vs[vr*VSTR + vc] = *(const bf16x8*)(Vp + (size_t)vr*SEQ + k0 + vc);
      }
      __syncthreads();

      // S^T = K Q^T : sacc[j][r] = S[key = k0+j*16+g*4+r][q = qrow]
      f32x4 sacc[4] = {};
      #pragma unroll
      for (int ks = 0; ks < 4; ++ks) {
        bf16x8 bk[4];
        #pragma unroll
        for (int j = 0; j < 4; ++j) bk[j] = ld_frag(&Ks[(j*16 + fr)*KSTR + ks*32 + fo]);
        __builtin_amdgcn_s_setprio(1);
        #pragma unroll
        for (int j = 0; j < 4; ++j) sacc[j] = MFMA_BF16(bk[j], qf[ks], sacc[j]);
        __builtin_amdgcn_s_setprio(0);
      }

      // scale + causal mask, in place (lane owns 16 keys of q-row `qrow`)
      const bool diag = (kt == qt);
      #pragma unroll
      for (int j = 0; j < 4; ++j)
        #pragma unroll
        for (int r = 0; r < 4; ++r) {
          float v = sacc[j][r] * 0.08838834764831845f;  // 1/sqrt(128)
          if (diag && (k0 + j*16 + g*4 + r > qrow)) v = NEG_BIG;
          sacc[j][r] = v;
        }

      // row max: 15 local + 2 cross-group shfl
      float mt = sacc[0][0];
      #pragma unroll
      for (int j = 0; j < 4; ++j)
        #pragma unroll
        for (int r = 0; r < 4; ++r)
          if (j | r) mt = fmaxf(mt, sacc[j][r]);
      mt = fmaxf(mt, __shfl_xor(mt, 16, 64));
      mt = fmaxf(mt, __shfl_xor(mt, 32, 64));

      // T13 defer-max: only rescale when the max grew by > 8
      float alpha = 1.0f;
      if (!__all(mt <= m_i + 8.0f)) {
        float mn = fmaxf(m_i, mt);
        alpha = __expf(m_i - mn);
        m_i = mn;
        #pragma unroll
        for (int r = 0; r < 4; ++r) {
          float ar = __shfl(alpha, g*4 + r, 64);   // fr-space -> O-row space
          #pragma unroll
          for (int n = 0; n < 8; ++n) oacc[n][r] *= ar;
        }
      }

      // P = exp(S - m), row sum, pack to bf16 quads
      float lt = 0.f;
      uint2 pw[4];
      #pragma unroll
      for (int j = 0; j < 4; ++j) {
        float p0 = __expf(sacc[j][0] - m_i);
        float p1 = __expf(sacc[j][1] - m_i);
        float p2 = __expf(sacc[j][2] - m_i);
        float p3 = __expf(sacc[j][3] - m_i);
        lt += (p0 + p1) + (p2 + p3);
        union { uint16_t u[4]; uint2 v; } pk;
        pk.u[0] = f32_to_bf16(p0); pk.u[1] = f32_to_bf16(p1);
        pk.u[2] = f32_to_bf16(p2); pk.u[3] = f32_to_bf16(p3);
        pw[j] = pk.v;
      }
      lt += __shfl_xor(lt, 16, 64);
      lt += __shfl_xor(lt, 32, 64);
      l_i = l_i * alpha + lt;

      __syncthreads();   // all waves finished reading Ks before P overwrites it

      // Ps[q = wave*16+fr][key = j*16 + g*4 + 0..3] — 4 x ds_write_b64
      #pragma unroll
      for (int j = 0; j < 4; ++j)
        *(uint2*)&Ps[(wave*16 + fr)*VSTR + j*16 + g*4] = pw[j];

      // O += P * V   (no barrier: own-strip Ps; Vs stable since staging)
      #pragma unroll
      for (int ks = 0; ks < 2; ++ks) {
        bf16x8 ap = ld_frag(&Ps[(wave*16 + fr)*VSTR + ks*32 + fo]);
        #pragma unroll
        for (int half = 0; half < 2; ++half) {
          bf16x8 bv[4];
          #pragma unroll
          for (int n = 0; n < 4; ++n)
            bv[n] = ld_frag(&Vs[((half*4 + n)*16 + fr)*VSTR + ks*32 + fo]);
          __builtin_amdgcn_s_setprio(1);
          #pragma unroll
          for (int n = 0; n < 4; ++n)
            oacc[half*4 + n] = MFMA_BF16(ap, bv[n], oacc[half*4 + n]);
          __builtin_amdgcn_s_setprio(0);
        }
      }
    }

    // epilogue: O over Q in-place; l lives in fr-space -> broadcast per O-row
    #pragma unroll
    for (int r = 0; r < 4; ++r) {
      float lr = __shfl(l_i, g*4 + r, 64);
      float inv_l = 1.0f / lr;
      #pragma unroll
      for (int n = 0; n < 8; ++n)
        Qh[(size_t)(orow_base + r)*HIDDEN + n*16 + fr] = f32_to_bf16(oacc[n][r] * inv_l);
    }
    __syncthreads();   // LDS/Q safe before next pass
  }
}

// ============================================================================
extern "C" void kernel_launch(void* const* d_in, const int* in_sizes, int n_in,
                              void* d_out, int out_size, void* d_ws, size_t ws_size,
                              hipStream_t stream)
{
  (void)in_sizes; (void)n_in; (void)out_size; (void)ws_size;
  const float* hidden = (const float*)d_in[0];   // fp32 per reference
  const float* wq = (const float*)d_in[2];
  const float* wk = (const float*)d_in[3];
  const float* wv = (const float*)d_in[4];
  const float* wo = (const float*)d_in[5];
  float* out = (float*)d_out;                    // fp32 per reference output

  // bf16 workspace with aliasing (~134 MB):
  //  R0: Xb (until qkv) -> Wob ; R1: Wqb (until qkv) -> Vt
  uint16_t* R0 = (uint16_t*)d_ws;                         // 16.78M elems
  uint16_t* R1 = R0 + (size_t)HIDDEN*HIDDEN;              // 16.78M
  uint16_t* R2 = R1 + (size_t)HIDDEN*HIDDEN;              //  4.19M
  uint16_t* R3 = R2 + (size_t)KVDIM*HIDDEN;               //  4.19M
  uint16_t* Qb = R3 + (size_t)KVDIM*HIDDEN;               // 16.78M
  uint16_t* Kb = Qb + (size_t)TOKENS*HIDDEN;              //  4.19M
  uint16_t* Vb = Kb + (size_t)TOKENS*KVDIM;               //  4.19M

  dim3 blk(256);
  cvt_all<<<dim3(20480), blk, 0, stream>>>(hidden, wq, wk, wv, R0, R1, R2, R3);
  qkv_gemm<<<dim3(48, TOKENS/128), blk, 0, stream>>>(R0, R1, R2, R3, Qb, Kb, Vb);
  rope_kernel<<<dim3(TOKENS*(NH+NKVH)*64/256), blk, 0, stream>>>(Qb, Kb);
  cvt_one<<<dim3(HIDDEN*HIDDEN/8/256), blk, 0, stream>>>(wo, R0);   // Wo -> R0 (Xb dead)
  transpose_v<<<dim3(SEQ/64, HD/64, BATCH*NKVH), blk, 0, stream>>>(Vb, R1); // Vt -> R1
  flash_attn<<<dim3(16, BATCH*NH), blk, 0, stream>>>(Qb, Kb, R1);
  out_gemm<<<dim3(HIDDEN/128, TOKENS/128), blk, 0, stream>>>(Qb, R0, out, HIDDEN, HIDDEN);
}

// Round 11
// 770.532 us; speedup vs baseline: 1.0908x; 1.0409x over previous
//
#include <hip/hip_runtime.h>
#include <stdint.h>

// ---- problem constants (MistralAttention: B=2,S=2048,H=32,KVH=8,D=128) ----
#define NH      32
#define NKVH    8
#define HD      128
#define BATCH   2
#define SEQ     2048
#define HIDDEN  4096
#define KVDIM   1024
#define TOKENS  (BATCH*SEQ)

typedef __bf16 bf16x8 __attribute__((ext_vector_type(8)));
typedef float  f32x4  __attribute__((ext_vector_type(4)));

__device__ __forceinline__ uint16_t f32_to_bf16(float f) {
  union { float f; uint32_t u; } v; v.f = f;
  uint32_t r = v.u + 0x7FFFu + ((v.u >> 16) & 1u);   // RNE
  return (uint16_t)(r >> 16);
}
__device__ __forceinline__ float bf16_to_f32(uint16_t h) {
  union { uint32_t u; float f; } v; v.u = ((uint32_t)h) << 16;
  return v.f;
}
__device__ __forceinline__ bf16x8 ld_frag(const uint16_t* p) {
  return *(const bf16x8*)p;
}
#define MFMA_BF16(a,b,c) __builtin_amdgcn_mfma_f32_16x16x32_bf16((a),(b),(c),0,0,0)
#define NEG_BIG (-1.0e30f)

typedef __attribute__((address_space(1))) void as1_void;
typedef __attribute__((address_space(3))) void as3_void;
// async global->LDS, 16B per lane; LDS dest = wave-uniform base + lane*16
__device__ __forceinline__ void gload_lds16(const void* g, void* l) {
  __builtin_amdgcn_global_load_lds((as1_void*)g, (as3_void*)l, 16, 0, 0);
}

// ============================================================================
// fp32 -> bf16 conversion; single kernel for X, Wq, Wk, Wv (exact grids)
// ============================================================================
__device__ __forceinline__ void cvt8(const float* __restrict__ s,
                                     uint16_t* __restrict__ d, size_t i) {
  const float4* sp = (const float4*)s + 2*i;
  float4 a = sp[0], b = sp[1];
  union { uint16_t u[8]; uint4 v; } o;
  o.u[0]=f32_to_bf16(a.x); o.u[1]=f32_to_bf16(a.y);
  o.u[2]=f32_to_bf16(a.z); o.u[3]=f32_to_bf16(a.w);
  o.u[4]=f32_to_bf16(b.x); o.u[5]=f32_to_bf16(b.y);
  o.u[6]=f32_to_bf16(b.z); o.u[7]=f32_to_bf16(b.w);
  ((uint4*)d)[i] = o.v;
}

// grid.x = 8192 + 8192 + 2048 + 2048 = 20480 blocks of 256 (exact, no tails)
__global__ __launch_bounds__(256) void cvt_all(
    const float* __restrict__ X,  const float* __restrict__ Wq,
    const float* __restrict__ Wk, const float* __restrict__ Wv,
    uint16_t* __restrict__ R0, uint16_t* __restrict__ R1,
    uint16_t* __restrict__ R2, uint16_t* __restrict__ R3)
{
  int blk = blockIdx.x;
  const float* s; uint16_t* d; int b0;
  if (blk < 8192)       { s = X;  d = R0; b0 = 0; }
  else if (blk < 16384) { s = Wq; d = R1; b0 = 8192; }
  else if (blk < 18432) { s = Wk; d = R2; b0 = 16384; }
  else                  { s = Wv; d = R3; b0 = 18432; }
  cvt8(s, d, (size_t)(blk - b0)*256 + threadIdx.x);
}

__global__ __launch_bounds__(256) void cvt_one(
    const float* __restrict__ s, uint16_t* __restrict__ d)
{
  cvt8(s, d, (size_t)blockIdx.x*256 + threadIdx.x);
}

// ============================================================================
// GEMM engine v4: m97 geometry + 3-slot ring + counted vmcnt(4) + T2 swizzle
// (used by qkv_gemm: grid 1536 = exactly 2 rounds at 3 blocks/CU)
// ============================================================================
__device__ __forceinline__ void store_c(uint16_t* p, float v) { *p = f32_to_bf16(v); }
__device__ __forceinline__ void store_c(float*    p, float v) { *p = v; }

template <typename TC>
__device__ __forceinline__ void gemm_body(
    const uint16_t* __restrict__ A, const uint16_t* __restrict__ B,
    TC* __restrict__ C, int m0, int n0, int N, int K)
{
  __shared__ __align__(16) uint16_t As[3][128*32];
  __shared__ __align__(16) uint16_t Bs[3][128*32];
  const int tid  = threadIdx.x;
  const int wave = tid >> 6;
  const int lane = tid & 63;
  const int wm = (wave >> 1) * 64;
  const int wn = (wave & 1) * 64;
  const int srow = lane >> 2;          // staging: 4 lanes x 16B per 64B row
  const int scol = (((lane & 3) ^ ((lane >> 3) & 3)) * 8);   // swizzled source
  const uint16_t* Ap = A + (size_t)(m0 + wave*16 + srow) * K + scol;
  const uint16_t* Bp = B + (size_t)(n0 + wave*16 + srow) * K + scol;
  const int wuo = wave*16*32;          // wave-uniform strip offset (elements)
  const int fr = lane & 15;
  const int fo = (((lane >> 4) ^ ((fr >> 1) & 3)) * 8);      // swizzled read
  const int NT = K / 32;

  // prologue: stage tiles 0 and 1 into slots 0 and 1
  #pragma unroll
  for (int t = 0; t < 2; ++t) {
    gload_lds16(Ap + (size_t)t*32,                &As[t][wuo]);
    gload_lds16(Ap + (size_t)64*K + (size_t)t*32, &As[t][64*32 + wuo]);
    gload_lds16(Bp + (size_t)t*32,                &Bs[t][wuo]);
    gload_lds16(Bp + (size_t)64*K + (size_t)t*32, &Bs[t][64*32 + wuo]);
  }

  f32x4 acc[4][4] = {};
  int s_cur = 0, s_stage = 2;          // slot of tile t; slot for tile t+2
  for (int t = 0; t < NT; ++t) {
    // retire exactly tile t's 4 loads; keep tile t+1's 4 in flight
    if (t < NT - 1) asm volatile("s_waitcnt vmcnt(4)" ::: "memory");
    else            asm volatile("s_waitcnt vmcnt(0)" ::: "memory");
    __builtin_amdgcn_s_barrier();
    asm volatile("" ::: "memory");

    // stage tile t+2 into the slot tile t-1 occupied (dead past the barrier)
    if (t + 2 < NT) {
      const size_t k2 = (size_t)(t + 2) * 32;
      gload_lds16(Ap + k2,                &As[s_stage][wuo]);
      gload_lds16(Ap + (size_t)64*K + k2, &As[s_stage][64*32 + wuo]);
      gload_lds16(Bp + k2,                &Bs[s_stage][wuo]);
      gload_lds16(Bp + (size_t)64*K + k2, &Bs[s_stage][64*32 + wuo]);
    }

    const uint16_t* Asb = As[s_cur];
    const uint16_t* Bsb = Bs[s_cur];
    bf16x8 af[4], bfr[4];
    #pragma unroll
    for (int i = 0; i < 4; ++i) af[i]  = ld_frag(&Asb[(wm + i*16 + fr)*32 + fo]);
    #pragma unroll
    for (int j = 0; j < 4; ++j) bfr[j] = ld_frag(&Bsb[(wn + j*16 + fr)*32 + fo]);
    __builtin_amdgcn_s_setprio(1);
    #pragma unroll
    for (int i = 0; i < 4; ++i)
      #pragma unroll
      for (int j = 0; j < 4; ++j)
        acc[i][j] = MFMA_BF16(af[i], bfr[j], acc[i][j]);
    __builtin_amdgcn_s_setprio(0);

    s_cur   = (s_cur   == 2) ? 0 : s_cur + 1;
    s_stage = (s_stage == 2) ? 0 : s_stage + 1;
  }

  const int cr = (lane >> 4) * 4;      // C layout: col=lane&15, row=(lane>>4)*4+reg
  const int cfr = lane & 15;
  #pragma unroll
  for (int i = 0; i < 4; ++i)
    #pragma unroll
    for (int j = 0; j < 4; ++j)
      #pragma unroll
      for (int r = 0; r < 4; ++r)
        store_c(&C[(size_t)(m0 + wm + i*16 + cr + r) * N + (n0 + wn + j*16 + cfr)],
                acc[i][j][r]);
}

// ============================================================================
// GEMM engine v5 (out_gemm only): NBUF=2 double-buffer, 32KB LDS -> 4
// blocks/CU; grid 32x32 = 1024 blocks = EXACTLY one full device round
// (fixes the 1.5x grid-tail at 3/CU: round2 ran 256 blocks at 1/3 util).
// Sync: per iter, vmcnt(0) retires tile t's loads (only outstanding);
// barrier globalizes AND certifies slot (t+1)&1's tile t-1 reads (done in
// iter t-1); stage(t+1) then writes the disjoint slot while we compute t.
// Fragment/swizzle code identical to v4.
// ============================================================================
template <typename TC>
__device__ __forceinline__ void gemm_body2(
    const uint16_t* __restrict__ A, const uint16_t* __restrict__ B,
    TC* __restrict__ C, int m0, int n0, int N, int K)
{
  __shared__ __align__(16) uint16_t As[2][128*32];
  __shared__ __align__(16) uint16_t Bs[2][128*32];
  const int tid  = threadIdx.x;
  const int wave = tid >> 6;
  const int lane = tid & 63;
  const int wm = (wave >> 1) * 64;
  const int wn = (wave & 1) * 64;
  const int srow = lane >> 2;
  const int scol = (((lane & 3) ^ ((lane >> 3) & 3)) * 8);   // swizzled source
  const uint16_t* Ap = A + (size_t)(m0 + wave*16 + srow) * K + scol;
  const uint16_t* Bp = B + (size_t)(n0 + wave*16 + srow) * K + scol;
  const int wuo = wave*16*32;
  const int fr = lane & 15;
  const int fo = (((lane >> 4) ^ ((fr >> 1) & 3)) * 8);      // swizzled read
  const int NT = K / 32;

  // prologue: stage tile 0 into slot 0
  gload_lds16(Ap,                &As[0][wuo]);
  gload_lds16(Ap + (size_t)64*K, &As[0][64*32 + wuo]);
  gload_lds16(Bp,                &Bs[0][wuo]);
  gload_lds16(Bp + (size_t)64*K, &Bs[0][64*32 + wuo]);

  f32x4 acc[4][4] = {};
  for (int t = 0; t < NT; ++t) {
    asm volatile("s_waitcnt vmcnt(0)" ::: "memory");   // tile t landed
    __builtin_amdgcn_s_barrier();
    asm volatile("" ::: "memory");

    // stage tile t+1 into slot (t+1)&1 (held t-1; reads done before barrier)
    if (t + 1 < NT) {
      const int s = (t + 1) & 1;
      const size_t k1 = (size_t)(t + 1) * 32;
      gload_lds16(Ap + k1,                &As[s][wuo]);
      gload_lds16(Ap + (size_t)64*K + k1, &As[s][64*32 + wuo]);
      gload_lds16(Bp + k1,                &Bs[s][wuo]);
      gload_lds16(Bp + (size_t)64*K + k1, &Bs[s][64*32 + wuo]);
    }

    const uint16_t* Asb = As[t & 1];
    const uint16_t* Bsb = Bs[t & 1];
    bf16x8 af[4], bfr[4];
    #pragma unroll
    for (int i = 0; i < 4; ++i) af[i]  = ld_frag(&Asb[(wm + i*16 + fr)*32 + fo]);
    #pragma unroll
    for (int j = 0; j < 4; ++j) bfr[j] = ld_frag(&Bsb[(wn + j*16 + fr)*32 + fo]);
    __builtin_amdgcn_s_setprio(1);
    #pragma unroll
    for (int i = 0; i < 4; ++i)
      #pragma unroll
      for (int j = 0; j < 4; ++j)
        acc[i][j] = MFMA_BF16(af[i], bfr[j], acc[i][j]);
    __builtin_amdgcn_s_setprio(0);
  }

  const int cr = (lane >> 4) * 4;
  const int cfr = lane & 15;
  #pragma unroll
  for (int i = 0; i < 4; ++i)
    #pragma unroll
    for (int j = 0; j < 4; ++j)
      #pragma unroll
      for (int r = 0; r < 4; ++r)
        store_c(&C[(size_t)(m0 + wm + i*16 + cr + r) * N + (n0 + wn + j*16 + cfr)],
                acc[i][j][r]);
}

// fused Q/K/V projection: grid.x = 32 (Q) + 8 (K) + 8 (V); grid 48x32=1536
__global__ __launch_bounds__(256, 3) void qkv_gemm(
    const uint16_t* __restrict__ X,
    const uint16_t* __restrict__ Wq, const uint16_t* __restrict__ Wk,
    const uint16_t* __restrict__ Wv,
    uint16_t* __restrict__ Qo, uint16_t* __restrict__ Ko, uint16_t* __restrict__ Vo)
{
  int bx = blockIdx.x;
  const uint16_t* B; uint16_t* C; int n0, N;
  if (bx < 32)      { B = Wq; C = Qo; n0 = bx*128;      N = HIDDEN; }
  else if (bx < 40) { B = Wk; C = Ko; n0 = (bx-32)*128; N = KVDIM;  }
  else              { B = Wv; C = Vo; n0 = (bx-40)*128; N = KVDIM;  }
  gemm_body<uint16_t>(X, B, C, blockIdx.y*128, n0, N, HIDDEN);
}

// final projection: C fp32 to d_out; NBUF=2 engine, 4 blocks/CU, 1 exact round
__global__ __launch_bounds__(256, 4) void out_gemm(
    const uint16_t* __restrict__ A, const uint16_t* __restrict__ B,
    float* __restrict__ C, int N, int K)
{
  gemm_body2<float>(A, B, C, blockIdx.y*128, blockIdx.x*128, N, K);
}

// ============================================================================
// RoPE in-place on Q [TOKENS,HIDDEN] and K [TOKENS,KVDIM] (bf16)
// ============================================================================
__global__ __launch_bounds__(256) void rope_kernel(
    uint16_t* __restrict__ Q, uint16_t* __restrict__ K)
{
  int idx = blockIdx.x * 256 + threadIdx.x;
  int j = idx & 63;
  int rest = idx >> 6;
  int h = rest % (NH + NKVH);
  int t = rest / (NH + NKVH);
  float pos = (float)(t % SEQ);
  float inv_freq = __exp10f(-0.0625f * (float)j);
  float ang = pos * inv_freq;
  float s, c;
  __sincosf(ang, &s, &c);
  uint16_t* base = (h < NH) ? (Q + (size_t)t*HIDDEN + h*HD)
                            : (K + (size_t)t*KVDIM + (h-NH)*HD);
  float x1 = bf16_to_f32(base[j]);
  float x2 = bf16_to_f32(base[j+64]);
  base[j]    = f32_to_bf16(x1*c - x2*s);
  base[j+64] = f32_to_bf16(x2*c + x1*s);
}

// ============================================================================
// V transpose: V[TOKENS,KVDIM](bf16) -> Vt[B][KVH][HD][SEQ](bf16)
// ============================================================================
__global__ __launch_bounds__(256) void transpose_v(
    const uint16_t* __restrict__ V, uint16_t* __restrict__ Vt)
{
  __shared__ uint16_t tile[64][66];
  int bh = blockIdx.z;  int b = bh >> 3, h = bh & 7;
  int s0 = blockIdx.x * 64;
  int d0 = blockIdx.y * 64;
  int tx = threadIdx.x & 63;
  int ty = threadIdx.x >> 6;
  const uint16_t* Vp = V + (size_t)b*SEQ*KVDIM + (size_t)h*HD;
  for (int r = ty; r < 64; r += 4)
    tile[r][tx] = Vp[(size_t)(s0 + r)*KVDIM + d0 + tx];
  __syncthreads();
  uint16_t* Vtp = Vt + ((size_t)b*NKVH + h)*HD*SEQ;
  for (int r = ty; r < 64; r += 4)
    Vtp[(size_t)(d0 + r)*SEQ + s0 + tx] = tile[tx][r];
}

// ============================================================================
// Flash attention v2 (causal, GQA): SWAPPED QK^T softmax. (measured: part of
// 802 µs pipeline, refcheck'd)
// ============================================================================
#define KSTR 136   // Ks row stride (128 cols + 8 pad)
#define VSTR 72    // Vs/Ps row stride (64 cols + 8 pad)

__global__ __launch_bounds__(256, 4) void flash_attn(
    uint16_t* __restrict__ Q, const uint16_t* __restrict__ K,
    const uint16_t* __restrict__ Vt)
{
  __shared__ __align__(16) uint16_t Ks[64*KSTR];    // 17.0 KB (Ps aliases this)
  __shared__ __align__(16) uint16_t Vs[128*VSTR];   // 18.0 KB
  uint16_t* Ps = Ks;  // [q=64][key=64] stride VSTR — fits in Ks region

  const int tid  = threadIdx.x;
  const int wave = tid >> 6;
  const int lane = tid & 63;
  const int fr = lane & 15;
  const int g  = lane >> 4;
  const int fo = g * 8;
  const int bh = blockIdx.y;
  const int b = bh >> 5, h = bh & 31;
  const int kvh = h >> 2;   // GQA: 4 Q-heads per KV-head

  uint16_t*       Qh = Q  + (size_t)b*SEQ*HIDDEN + (size_t)h*HD;
  const uint16_t* Kp = K  + (size_t)b*SEQ*KVDIM  + (size_t)kvh*HD;
  const uint16_t* Vp = Vt + ((size_t)b*NKVH + kvh)*HD*SEQ;

  #pragma unroll
  for (int pass = 0; pass < 2; ++pass) {
    const int qt = pass ? (31 - (int)blockIdx.x) : (int)blockIdx.x;
    const int q0 = qt * 64;
    const int qrow = q0 + wave*16 + fr;         // this lane's softmax q-row
    const int orow_base = q0 + wave*16 + g*4;   // + r = this lane's O rows

    // Q fragments: wave's 16 q-rows (row = fr), d=0..127
    bf16x8 qf[4];
    #pragma unroll
    for (int ks = 0; ks < 4; ++ks)
      qf[ks] = ld_frag(Qh + (size_t)(q0 + wave*16 + fr)*HIDDEN + ks*32 + fo);

    float m_i = NEG_BIG, l_i = 0.f;
    f32x4 oacc[8] = {};

    const int nkt = qt + 1;   // causal: keys up to q0+63
    for (int kt = 0; kt < nkt; ++kt) {
      const int k0 = kt * 64;
      __syncthreads();   // prev iter's Vs/Ps reads done before restaging
      #pragma unroll
      for (int i = 0; i < 4; ++i) {
        int gi = tid + i*256;                    // 0..1023
        int kr = gi >> 4, kc = (gi & 15) * 8;    // Ks: 64 x 128
        *(bf16x8*)&Ks[kr*KSTR + kc] = *(const bf16x8*)(Kp + (size_t)(k0 + kr)*KVDIM + kc);
        int vr = gi >> 3, vc = (gi & 7) * 8;     // Vs: 128 x 64
        *(bf16x8*)&Vs[vr*VSTR + vc] = *(const bf16x8*)(Vp + (size_t)vr*SEQ + k0 + vc);
      }
      __syncthreads();

      // S^T = K Q^T : sacc[j][r] = S[key = k0+j*16+g*4+r][q = qrow]
      f32x4 sacc[4] = {};
      #pragma unroll
      for (int ks = 0; ks < 4; ++ks) {
        bf16x8 bk[4];
        #pragma unroll
        for (int j = 0; j < 4; ++j) bk[j] = ld_frag(&Ks[(j*16 + fr)*KSTR + ks*32 + fo]);
        __builtin_amdgcn_s_setprio(1);
        #pragma unroll
        for (int j = 0; j < 4; ++j) sacc[j] = MFMA_BF16(bk[j], qf[ks], sacc[j]);
        __builtin_amdgcn_s_setprio(0);
      }

      // scale + causal mask, in place (lane owns 16 keys of q-row `qrow`)
      const bool diag = (kt == qt);
      #pragma unroll
      for (int j = 0; j < 4; ++j)
        #pragma unroll
        for (int r = 0; r < 4; ++r) {
          float v = sacc[j][r] * 0.08838834764831845f;  // 1/sqrt(128)
          if (diag && (k0 + j*16 + g*4 + r > qrow)) v = NEG_BIG;
          sacc[j][r] = v;
        }

      // row max: 15 local + 2 cross-group shfl
      float mt = sacc[0][0];
      #pragma unroll
      for (int j = 0; j < 4; ++j)
        #pragma unroll
        for (int r = 0; r < 4; ++r)
          if (j | r) mt = fmaxf(mt, sacc[j][r]);
      mt = fmaxf(mt, __shfl_xor(mt, 16, 64));
      mt = fmaxf(mt, __shfl_xor(mt, 32, 64));

      // T13 defer-max: only rescale when the max grew by > 8
      float alpha = 1.0f;
      if (!__all(mt <= m_i + 8.0f)) {
        float mn = fmaxf(m_i, mt);
        alpha = __expf(m_i - mn);
        m_i = mn;
        #pragma unroll
        for (int r = 0; r < 4; ++r) {
          float ar = __shfl(alpha, g*4 + r, 64);   // fr-space -> O-row space
          #pragma unroll
          for (int n = 0; n < 8; ++n) oacc[n][r] *= ar;
        }
      }

      // P = exp(S - m), row sum, pack to bf16 quads
      float lt = 0.f;
      uint2 pw[4];
      #pragma unroll
      for (int j = 0; j < 4; ++j) {
        float p0 = __expf(sacc[j][0] - m_i);
        float p1 = __expf(sacc[j][1] - m_i);
        float p2 = __expf(sacc[j][2] - m_i);
        float p3 = __expf(sacc[j][3] - m_i);
        lt += (p0 + p1) + (p2 + p3);
        union { uint16_t u[4]; uint2 v; } pk;
        pk.u[0] = f32_to_bf16(p0); pk.u[1] = f32_to_bf16(p1);
        pk.u[2] = f32_to_bf16(p2); pk.u[3] = f32_to_bf16(p3);
        pw[j] = pk.v;
      }
      lt += __shfl_xor(lt, 16, 64);
      lt += __shfl_xor(lt, 32, 64);
      l_i = l_i * alpha + lt;

      __syncthreads();   // all waves finished reading Ks before P overwrites it

      // Ps[q = wave*16+fr][key = j*16 + g*4 + 0..3] — 4 x ds_write_b64
      #pragma unroll
      for (int j = 0; j < 4; ++j)
        *(uint2*)&Ps[(wave*16 + fr)*VSTR + j*16 + g*4] = pw[j];

      // O += P * V   (no barrier: own-strip Ps; Vs stable since staging)
      #pragma unroll
      for (int ks = 0; ks < 2; ++ks) {
        bf16x8 ap = ld_frag(&Ps[(wave*16 + fr)*VSTR + ks*32 + fo]);
        #pragma unroll
        for (int half = 0; half < 2; ++half) {
          bf16x8 bv[4];
          #pragma unroll
          for (int n = 0; n < 4; ++n)
            bv[n] = ld_frag(&Vs[((half*4 + n)*16 + fr)*VSTR + ks*32 + fo]);
          __builtin_amdgcn_s_setprio(1);
          #pragma unroll
          for (int n = 0; n < 4; ++n)
            oacc[half*4 + n] = MFMA_BF16(ap, bv[n], oacc[half*4 + n]);
          __builtin_amdgcn_s_setprio(0);
        }
      }
    }

    // epilogue: O over Q in-place; l lives in fr-space -> broadcast per O-row
    #pragma unroll
    for (int r = 0; r < 4; ++r) {
      float lr = __shfl(l_i, g*4 + r, 64);
      float inv_l = 1.0f / lr;
      #pragma unroll
      for (int n = 0; n < 8; ++n)
        Qh[(size_t)(orow_base + r)*HIDDEN + n*16 + fr] = f32_to_bf16(oacc[n][r] * inv_l);
    }
    __syncthreads();   // LDS/Q safe before next pass
  }
}

// ============================================================================
extern "C" void kernel_launch(void* const* d_in, const int* in_sizes, int n_in,
                              void* d_out, int out_size, void* d_ws, size_t ws_size,
                              hipStream_t stream)
{
  (void)in_sizes; (void)n_in; (void)out_size; (void)ws_size;
  const float* hidden = (const float*)d_in[0];   // fp32 per reference
  const float* wq = (const float*)d_in[2];
  const float* wk = (const float*)d_in[3];
  const float* wv = (const float*)d_in[4];
  const float* wo = (const float*)d_in[5];
  float* out = (float*)d_out;                    // fp32 per reference output

  // bf16 workspace with aliasing (~134 MB):
  //  R0: Xb (until qkv) -> Wob ; R1: Wqb (until qkv) -> Vt
  uint16_t* R0 = (uint16_t*)d_ws;                         // 16.78M elems
  uint16_t* R1 = R0 + (size_t)HIDDEN*HIDDEN;              // 16.78M
  uint16_t* R2 = R1 + (size_t)HIDDEN*HIDDEN;              //  4.19M
  uint16_t* R3 = R2 + (size_t)KVDIM*HIDDEN;               //  4.19M
  uint16_t* Qb = R3 + (size_t)KVDIM*HIDDEN;               // 16.78M
  uint16_t* Kb = Qb + (size_t)TOKENS*HIDDEN;              //  4.19M
  uint16_t* Vb = Kb + (size_t)TOKENS*KVDIM;               //  4.19M

  dim3 blk(256);
  cvt_all<<<dim3(20480), blk, 0, stream>>>(hidden, wq, wk, wv, R0, R1, R2, R3);
  qkv_gemm<<<dim3(48, TOKENS/128), blk, 0, stream>>>(R0, R1, R2, R3, Qb, Kb, Vb);
  rope_kernel<<<dim3(TOKENS*(NH+NKVH)*64/256), blk, 0, stream>>>(Qb, Kb);
  cvt_one<<<dim3(HIDDEN*HIDDEN/8/256), blk, 0, stream>>>(wo, R0);   // Wo -> R0 (Xb dead)
  transpose_v<<<dim3(SEQ/64, HD/64, BATCH*NKVH), blk, 0, stream>>>(Vb, R1); // Vt -> R1
  flash_attn<<<dim3(16, BATCH*NH), blk, 0, stream>>>(Qb, Kb, R1);
  out_gemm<<<dim3(HIDDEN/128, TOKENS/128), blk, 0, stream>>>(Qb, R0, out, HIDDEN, HIDDEN);
}

// Round 13
// 760.064 us; speedup vs baseline: 1.1058x; 1.0138x over previous
//
#include <hip/hip_runtime.h>
#include <stdint.h>

// ---- problem constants (MistralAttention: B=2,S=2048,H=32,KVH=8,D=128) ----
#define NH      32
#define NKVH    8
#define HD      128
#define BATCH   2
#define SEQ     2048
#define HIDDEN  4096
#define KVDIM   1024
#define TOKENS  (BATCH*SEQ)

typedef __bf16 bf16x8 __attribute__((ext_vector_type(8)));
typedef float  f32x4  __attribute__((ext_vector_type(4)));

__device__ __forceinline__ uint16_t f32_to_bf16(float f) {
  union { float f; uint32_t u; } v; v.f = f;
  uint32_t r = v.u + 0x7FFFu + ((v.u >> 16) & 1u);   // RNE
  return (uint16_t)(r >> 16);
}
__device__ __forceinline__ float bf16_to_f32(uint16_t h) {
  union { uint32_t u; float f; } v; v.u = ((uint32_t)h) << 16;
  return v.f;
}
__device__ __forceinline__ bf16x8 ld_frag(const uint16_t* p) {
  return *(const bf16x8*)p;
}
#define MFMA_BF16(a,b,c) __builtin_amdgcn_mfma_f32_16x16x32_bf16((a),(b),(c),0,0,0)
#define NEG_BIG (-1.0e30f)

typedef __attribute__((address_space(1))) void as1_void;
typedef __attribute__((address_space(3))) void as3_void;
// async global->LDS, 16B per lane; LDS dest = wave-uniform base + lane*16
__device__ __forceinline__ void gload_lds16(const void* g, void* l) {
  __builtin_amdgcn_global_load_lds((as1_void*)g, (as3_void*)l, 16, 0, 0);
}

// ============================================================================
// fp32 -> bf16 conversion; single kernel for X, Wq, Wk, Wv (exact grids)
// ============================================================================
__device__ __forceinline__ void cvt8(const float* __restrict__ s,
                                     uint16_t* __restrict__ d, size_t i) {
  const float4* sp = (const float4*)s + 2*i;
  float4 a = sp[0], b = sp[1];
  union { uint16_t u[8]; uint4 v; } o;
  o.u[0]=f32_to_bf16(a.x); o.u[1]=f32_to_bf16(a.y);
  o.u[2]=f32_to_bf16(a.z); o.u[3]=f32_to_bf16(a.w);
  o.u[4]=f32_to_bf16(b.x); o.u[5]=f32_to_bf16(b.y);
  o.u[6]=f32_to_bf16(b.z); o.u[7]=f32_to_bf16(b.w);
  ((uint4*)d)[i] = o.v;
}

// grid.x = 8192 + 8192 + 2048 + 2048 = 20480 blocks of 256 (exact, no tails)
__global__ __launch_bounds__(256) void cvt_all(
    const float* __restrict__ X,  const float* __restrict__ Wq,
    const float* __restrict__ Wk, const float* __restrict__ Wv,
    uint16_t* __restrict__ R0, uint16_t* __restrict__ R1,
    uint16_t* __restrict__ R2, uint16_t* __restrict__ R3)
{
  int blk = blockIdx.x;
  const float* s; uint16_t* d; int b0;
  if (blk < 8192)       { s = X;  d = R0; b0 = 0; }
  else if (blk < 16384) { s = Wq; d = R1; b0 = 8192; }
  else if (blk < 18432) { s = Wk; d = R2; b0 = 16384; }
  else                  { s = Wv; d = R3; b0 = 18432; }
  cvt8(s, d, (size_t)(blk - b0)*256 + threadIdx.x);
}

__global__ __launch_bounds__(256) void cvt_one(
    const float* __restrict__ s, uint16_t* __restrict__ d)
{
  cvt8(s, d, (size_t)blockIdx.x*256 + threadIdx.x);
}

// ============================================================================
// GEMM engine v4: m97 geometry + 3-slot ring + counted vmcnt(4) + T2 swizzle
// (used by qkv_gemm: grid 1536 = exactly 2 rounds at 3 blocks/CU)
// ============================================================================
__device__ __forceinline__ void store_c(uint16_t* p, float v) { *p = f32_to_bf16(v); }
__device__ __forceinline__ void store_c(float*    p, float v) { *p = v; }

template <typename TC>
__device__ __forceinline__ void gemm_body(
    const uint16_t* __restrict__ A, const uint16_t* __restrict__ B,
    TC* __restrict__ C, int m0, int n0, int N, int K)
{
  __shared__ __align__(16) uint16_t As[3][128*32];
  __shared__ __align__(16) uint16_t Bs[3][128*32];
  const int tid  = threadIdx.x;
  const int wave = tid >> 6;
  const int lane = tid & 63;
  const int wm = (wave >> 1) * 64;
  const int wn = (wave & 1) * 64;
  const int srow = lane >> 2;          // staging: 4 lanes x 16B per 64B row
  const int scol = (((lane & 3) ^ ((lane >> 3) & 3)) * 8);   // swizzled source
  const uint16_t* Ap = A + (size_t)(m0 + wave*16 + srow) * K + scol;
  const uint16_t* Bp = B + (size_t)(n0 + wave*16 + srow) * K + scol;
  const int wuo = wave*16*32;          // wave-uniform strip offset (elements)
  const int fr = lane & 15;
  const int fo = (((lane >> 4) ^ ((fr >> 1) & 3)) * 8);      // swizzled read
  const int NT = K / 32;

  // prologue: stage tiles 0 and 1 into slots 0 and 1
  #pragma unroll
  for (int t = 0; t < 2; ++t) {
    gload_lds16(Ap + (size_t)t*32,                &As[t][wuo]);
    gload_lds16(Ap + (size_t)64*K + (size_t)t*32, &As[t][64*32 + wuo]);
    gload_lds16(Bp + (size_t)t*32,                &Bs[t][wuo]);
    gload_lds16(Bp + (size_t)64*K + (size_t)t*32, &Bs[t][64*32 + wuo]);
  }

  f32x4 acc[4][4] = {};
  int s_cur = 0, s_stage = 2;          // slot of tile t; slot for tile t+2
  for (int t = 0; t < NT; ++t) {
    // retire exactly tile t's 4 loads; keep tile t+1's 4 in flight
    if (t < NT - 1) asm volatile("s_waitcnt vmcnt(4)" ::: "memory");
    else            asm volatile("s_waitcnt vmcnt(0)" ::: "memory");
    __builtin_amdgcn_s_barrier();
    asm volatile("" ::: "memory");

    // stage tile t+2 into the slot tile t-1 occupied (dead past the barrier)
    if (t + 2 < NT) {
      const size_t k2 = (size_t)(t + 2) * 32;
      gload_lds16(Ap + k2,                &As[s_stage][wuo]);
      gload_lds16(Ap + (size_t)64*K + k2, &As[s_stage][64*32 + wuo]);
      gload_lds16(Bp + k2,                &Bs[s_stage][wuo]);
      gload_lds16(Bp + (size_t)64*K + k2, &Bs[s_stage][64*32 + wuo]);
    }

    const uint16_t* Asb = As[s_cur];
    const uint16_t* Bsb = Bs[s_cur];
    bf16x8 af[4], bfr[4];
    #pragma unroll
    for (int i = 0; i < 4; ++i) af[i]  = ld_frag(&Asb[(wm + i*16 + fr)*32 + fo]);
    #pragma unroll
    for (int j = 0; j < 4; ++j) bfr[j] = ld_frag(&Bsb[(wn + j*16 + fr)*32 + fo]);
    __builtin_amdgcn_s_setprio(1);
    #pragma unroll
    for (int i = 0; i < 4; ++i)
      #pragma unroll
      for (int j = 0; j < 4; ++j)
        acc[i][j] = MFMA_BF16(af[i], bfr[j], acc[i][j]);
    __builtin_amdgcn_s_setprio(0);

    s_cur   = (s_cur   == 2) ? 0 : s_cur + 1;
    s_stage = (s_stage == 2) ? 0 : s_stage + 1;
  }

  const int cr = (lane >> 4) * 4;      // C layout: col=lane&15, row=(lane>>4)*4+reg
  const int cfr = lane & 15;
  #pragma unroll
  for (int i = 0; i < 4; ++i)
    #pragma unroll
    for (int j = 0; j < 4; ++j)
      #pragma unroll
      for (int r = 0; r < 4; ++r)
        store_c(&C[(size_t)(m0 + wm + i*16 + cr + r) * N + (n0 + wn + j*16 + cfr)],
                acc[i][j][r]);
}

// ============================================================================
// GEMM engine v5 (out_gemm only): NBUF=2 double-buffer, 32KB LDS -> 4
// blocks/CU; grid 32x32 = 1024 blocks = EXACTLY one full device round.
// (measured R11: out ~204 us, 672 TF — 2-phase drain rate, tail removed)
// ============================================================================
template <typename TC>
__device__ __forceinline__ void gemm_body2(
    const uint16_t* __restrict__ A, const uint16_t* __restrict__ B,
    TC* __restrict__ C, int m0, int n0, int N, int K)
{
  __shared__ __align__(16) uint16_t As[2][128*32];
  __shared__ __align__(16) uint16_t Bs[2][128*32];
  const int tid  = threadIdx.x;
  const int wave = tid >> 6;
  const int lane = tid & 63;
  const int wm = (wave >> 1) * 64;
  const int wn = (wave & 1) * 64;
  const int srow = lane >> 2;
  const int scol = (((lane & 3) ^ ((lane >> 3) & 3)) * 8);   // swizzled source
  const uint16_t* Ap = A + (size_t)(m0 + wave*16 + srow) * K + scol;
  const uint16_t* Bp = B + (size_t)(n0 + wave*16 + srow) * K + scol;
  const int wuo = wave*16*32;
  const int fr = lane & 15;
  const int fo = (((lane >> 4) ^ ((fr >> 1) & 3)) * 8);      // swizzled read
  const int NT = K / 32;

  // prologue: stage tile 0 into slot 0
  gload_lds16(Ap,                &As[0][wuo]);
  gload_lds16(Ap + (size_t)64*K, &As[0][64*32 + wuo]);
  gload_lds16(Bp,                &Bs[0][wuo]);
  gload_lds16(Bp + (size_t)64*K, &Bs[0][64*32 + wuo]);

  f32x4 acc[4][4] = {};
  for (int t = 0; t < NT; ++t) {
    asm volatile("s_waitcnt vmcnt(0)" ::: "memory");   // tile t landed
    __builtin_amdgcn_s_barrier();
    asm volatile("" ::: "memory");

    // stage tile t+1 into slot (t+1)&1 (held t-1; reads done before barrier)
    if (t + 1 < NT) {
      const int s = (t + 1) & 1;
      const size_t k1 = (size_t)(t + 1) * 32;
      gload_lds16(Ap + k1,                &As[s][wuo]);
      gload_lds16(Ap + (size_t)64*K + k1, &As[s][64*32 + wuo]);
      gload_lds16(Bp + k1,                &Bs[s][wuo]);
      gload_lds16(Bp + (size_t)64*K + k1, &Bs[s][64*32 + wuo]);
    }

    const uint16_t* Asb = As[t & 1];
    const uint16_t* Bsb = Bs[t & 1];
    bf16x8 af[4], bfr[4];
    #pragma unroll
    for (int i = 0; i < 4; ++i) af[i]  = ld_frag(&Asb[(wm + i*16 + fr)*32 + fo]);
    #pragma unroll
    for (int j = 0; j < 4; ++j) bfr[j] = ld_frag(&Bsb[(wn + j*16 + fr)*32 + fo]);
    __builtin_amdgcn_s_setprio(1);
    #pragma unroll
    for (int i = 0; i < 4; ++i)
      #pragma unroll
      for (int j = 0; j < 4; ++j)
        acc[i][j] = MFMA_BF16(af[i], bfr[j], acc[i][j]);
    __builtin_amdgcn_s_setprio(0);
  }

  const int cr = (lane >> 4) * 4;
  const int cfr = lane & 15;
  #pragma unroll
  for (int i = 0; i < 4; ++i)
    #pragma unroll
    for (int j = 0; j < 4; ++j)
      #pragma unroll
      for (int r = 0; r < 4; ++r)
        store_c(&C[(size_t)(m0 + wm + i*16 + cr + r) * N + (n0 + wn + j*16 + cfr)],
                acc[i][j][r]);
}

// fused Q/K/V projection: grid.x = 32 (Q) + 8 (K) + 8 (V); grid 48x32=1536
__global__ __launch_bounds__(256, 3) void qkv_gemm(
    const uint16_t* __restrict__ X,
    const uint16_t* __restrict__ Wq, const uint16_t* __restrict__ Wk,
    const uint16_t* __restrict__ Wv,
    uint16_t* __restrict__ Qo, uint16_t* __restrict__ Ko, uint16_t* __restrict__ Vo)
{
  int bx = blockIdx.x;
  const uint16_t* B; uint16_t* C; int n0, N;
  if (bx < 32)      { B = Wq; C = Qo; n0 = bx*128;      N = HIDDEN; }
  else if (bx < 40) { B = Wk; C = Ko; n0 = (bx-32)*128; N = KVDIM;  }
  else              { B = Wv; C = Vo; n0 = (bx-40)*128; N = KVDIM;  }
  gemm_body<uint16_t>(X, B, C, blockIdx.y*128, n0, N, HIDDEN);
}

// final projection: C fp32 to d_out; NBUF=2 engine, 4 blocks/CU, 1 exact round
__global__ __launch_bounds__(256, 4) void out_gemm(
    const uint16_t* __restrict__ A, const uint16_t* __restrict__ B,
    float* __restrict__ C, int N, int K)
{
  gemm_body2<float>(A, B, C, blockIdx.y*128, blockIdx.x*128, N, K);
}

// ============================================================================
// RoPE in-place on Q [TOKENS,HIDDEN] and K [TOKENS,KVDIM] (bf16)
// ============================================================================
__global__ __launch_bounds__(256) void rope_kernel(
    uint16_t* __restrict__ Q, uint16_t* __restrict__ K)
{
  int idx = blockIdx.x * 256 + threadIdx.x;
  int j = idx & 63;
  int rest = idx >> 6;
  int h = rest % (NH + NKVH);
  int t = rest / (NH + NKVH);
  float pos = (float)(t % SEQ);
  float inv_freq = __exp10f(-0.0625f * (float)j);
  float ang = pos * inv_freq;
  float s, c;
  __sincosf(ang, &s, &c);
  uint16_t* base = (h < NH) ? (Q + (size_t)t*HIDDEN + h*HD)
                            : (K + (size_t)t*KVDIM + (h-NH)*HD);
  float x1 = bf16_to_f32(base[j]);
  float x2 = bf16_to_f32(base[j+64]);
  base[j]    = f32_to_bf16(x1*c - x2*s);
  base[j+64] = f32_to_bf16(x2*c + x1*s);
}

// ============================================================================
// V transpose: V[TOKENS,KVDIM](bf16) -> Vt[B][KVH][HD][SEQ](bf16)
// ============================================================================
__global__ __launch_bounds__(256) void transpose_v(
    const uint16_t* __restrict__ V, uint16_t* __restrict__ Vt)
{
  __shared__ uint16_t tile[64][66];
  int bh = blockIdx.z;  int b = bh >> 3, h = bh & 7;
  int s0 = blockIdx.x * 64;
  int d0 = blockIdx.y * 64;
  int tx = threadIdx.x & 63;
  int ty = threadIdx.x >> 6;
  const uint16_t* Vp = V + (size_t)b*SEQ*KVDIM + (size_t)h*HD;
  for (int r = ty; r < 64; r += 4)
    tile[r][tx] = Vp[(size_t)(s0 + r)*KVDIM + d0 + tx];
  __syncthreads();
  uint16_t* Vtp = Vt + ((size_t)b*NKVH + h)*HD*SEQ;
  for (int r = ty; r < 64; r += 4)
    Vtp[(size_t)(d0 + r)*SEQ + s0 + tx] = tile[tx][r];
}

// ============================================================================
// Flash attention v3 (causal, GQA): swapped QK^T softmax (v2, measured win)
//  + gload_lds staging for K/V (m151: direct-to-LDS beats reg-staging).
//  Rule #21 both-sides swizzle: LINEAR LDS tiles, pre-swizzled per-lane
//  GLOBAL source slot, matching XOR on ds_read offset.
//   Ks[64][128] (16 slots/row of 16B): LDS[row][p] holds K[row][p^(row&15)];
//     read at phys (ks*4+g)^fr, row j*16+fr -> logical slot ks*4+g. 16-lane
//     read phase hits 16 distinct slots -> conflict-free.
//   Vs[128][64] (8 slots/row): LDS[row][p] holds V[row][p^(row&7)]; read at
//     (ks*4+g)^(fr&7) -> logical ks*4+g. 2 lanes/slot per phase = free (m136).
//  Sync unchanged: the existing __syncthreads() pair drains vmcnt for
//  gload_lds (syncthreads emits s_waitcnt vmcnt(0) lgkmcnt(0) + barrier).
//  Ps aliases Ks (9.2KB <= 16KB), layout unchanged. LDS 32KB -> 4 blocks/CU.
// ============================================================================
#define VSTR 72    // Ps row stride (64 cols + 8 pad), aliased into Ks region

__global__ __launch_bounds__(256, 4) void flash_attn(
    uint16_t* __restrict__ Q, const uint16_t* __restrict__ K,
    const uint16_t* __restrict__ Vt)
{
  __shared__ __align__(16) uint16_t Ks[64*128];     // 16KB linear, XOR-swizzled
  __shared__ __align__(16) uint16_t Vs[128*64];     // 16KB linear, XOR-swizzled
  uint16_t* Ps = Ks;  // [q=64][key=64] stride VSTR — aliased (Ks dead by then)

  const int tid  = threadIdx.x;
  const int wave = tid >> 6;
  const int lane = tid & 63;
  const int fr = lane & 15;
  const int g  = lane >> 4;
  const int fo = g * 8;
  const int bh = blockIdx.y;
  const int b = bh >> 5, h = bh & 31;
  const int kvh = h >> 2;   // GQA: 4 Q-heads per KV-head

  uint16_t*       Qh = Q  + (size_t)b*SEQ*HIDDEN + (size_t)h*HD;
  const uint16_t* Kp = K  + (size_t)b*SEQ*KVDIM  + (size_t)kvh*HD;
  const uint16_t* Vp = Vt + ((size_t)b*NKVH + kvh)*HD*SEQ;

  // staging lane constants (pre-swizzled global slot; linear LDS dest)
  const int krl = lane >> 4;                    // K: row-within-4 (16 lanes/row)
  const int ksl = lane & 15;                    // K: dest slot
  const int vrl = lane >> 3;                    // V: row-within-8 (8 lanes/row)
  const int vsl = lane & 7;                     // V: dest slot
  const int vswz = vsl ^ (vrl & 7);             // V: global slot (row&7 = vrl&7)

  #pragma unroll
  for (int pass = 0; pass < 2; ++pass) {
    const int qt = pass ? (31 - (int)blockIdx.x) : (int)blockIdx.x;
    const int q0 = qt * 64;
    const int qrow = q0 + wave*16 + fr;         // this lane's softmax q-row
    const int orow_base = q0 + wave*16 + g*4;   // + r = this lane's O rows

    // Q fragments: wave's 16 q-rows (row = fr), d=0..127
    bf16x8 qf[4];
    #pragma unroll
    for (int ks = 0; ks < 4; ++ks)
      qf[ks] = ld_frag(Qh + (size_t)(q0 + wave*16 + fr)*HIDDEN + ks*32 + fo);

    float m_i = NEG_BIG, l_i = 0.f;
    f32x4 oacc[8] = {};

    const int nkt = qt + 1;   // causal: keys up to q0+63
    for (int kt = 0; kt < nkt; ++kt) {
      const int k0 = kt * 64;
      __syncthreads();   // prev iter's Vs/Ps reads done before restaging
      // K: wave w instr i covers rows [w*16+i*4, +4); lane -> row +krl, slot ksl
      //    source slot = ksl ^ (row & 15), row&15 = i*4 + krl
      // V: wave w instr i covers rows [w*32+i*8, +8); lane -> row +vrl, slot vsl
      #pragma unroll
      for (int i = 0; i < 4; ++i) {
        const int krow = wave*16 + i*4 + krl;
        const int kswz = ksl ^ ((i*4 + krl) & 15);
        gload_lds16(Kp + (size_t)(k0 + krow)*KVDIM + kswz*8,
                    &Ks[(wave*16 + i*4)*128]);
        const int vrow = wave*32 + i*8 + vrl;
        gload_lds16(Vp + (size_t)vrow*SEQ + k0 + vswz*8,
                    &Vs[(wave*32 + i*8)*64]);
      }
      __syncthreads();   // drains vmcnt(0)+lgkm, barriers: tiles ready

      // S^T = K Q^T : sacc[j][r] = S[key = k0+j*16+g*4+r][q = qrow]
      f32x4 sacc[4] = {};
      #pragma unroll
      for (int ks = 0; ks < 4; ++ks) {
        bf16x8 bk[4];
        #pragma unroll
        for (int j = 0; j < 4; ++j)
          bk[j] = ld_frag(&Ks[(j*16 + fr)*128 + ((ks*4 + g) ^ fr)*8]);
        __builtin_amdgcn_s_setprio(1);
        #pragma unroll
        for (int j = 0; j < 4; ++j) sacc[j] = MFMA_BF16(bk[j], qf[ks], sacc[j]);
        __builtin_amdgcn_s_setprio(0);
      }

      // scale + causal mask, in place (lane owns 16 keys of q-row `qrow`)
      const bool diag = (kt == qt);
      #pragma unroll
      for (int j = 0; j < 4; ++j)
        #pragma unroll
        for (int r = 0; r < 4; ++r) {
          float v = sacc[j][r] * 0.08838834764831845f;  // 1/sqrt(128)
          if (diag && (k0 + j*16 + g*4 + r > qrow)) v = NEG_BIG;
          sacc[j][r] = v;
        }

      // row max: 15 local + 2 cross-group shfl
      float mt = sacc[0][0];
      #pragma unroll
      for (int j = 0; j < 4; ++j)
        #pragma unroll
        for (int r = 0; r < 4; ++r)
          if (j | r) mt = fmaxf(mt, sacc[j][r]);
      mt = fmaxf(mt, __shfl_xor(mt, 16, 64));
      mt = fmaxf(mt, __shfl_xor(mt, 32, 64));

      // T13 defer-max: only rescale when the max grew by > 8
      float alpha = 1.0f;
      if (!__all(mt <= m_i + 8.0f)) {
        float mn = fmaxf(m_i, mt);
        alpha = __expf(m_i - mn);
        m_i = mn;
        #pragma unroll
        for (int r = 0; r < 4; ++r) {
          float ar = __shfl(alpha, g*4 + r, 64);   // fr-space -> O-row space
          #pragma unroll
          for (int n = 0; n < 8; ++n) oacc[n][r] *= ar;
        }
      }

      // P = exp(S - m), row sum, pack to bf16 quads
      float lt = 0.f;
      uint2 pw[4];
      #pragma unroll
      for (int j = 0; j < 4; ++j) {
        float p0 = __expf(sacc[j][0] - m_i);
        float p1 = __expf(sacc[j][1] - m_i);
        float p2 = __expf(sacc[j][2] - m_i);
        float p3 = __expf(sacc[j][3] - m_i);
        lt += (p0 + p1) + (p2 + p3);
        union { uint16_t u[4]; uint2 v; } pk;
        pk.u[0] = f32_to_bf16(p0); pk.u[1] = f32_to_bf16(p1);
        pk.u[2] = f32_to_bf16(p2); pk.u[3] = f32_to_bf16(p3);
        pw[j] = pk.v;
      }
      lt += __shfl_xor(lt, 16, 64);
      lt += __shfl_xor(lt, 32, 64);
      l_i = l_i * alpha + lt;

      __syncthreads();   // all waves finished reading Ks before P overwrites it

      // Ps[q = wave*16+fr][key = j*16 + g*4 + 0..3] — 4 x ds_write_b64
      #pragma unroll
      for (int j = 0; j < 4; ++j)
        *(uint2*)&Ps[(wave*16 + fr)*VSTR + j*16 + g*4] = pw[j];

      // O += P * V   (no barrier: own-strip Ps; Vs stable since staging)
      #pragma unroll
      for (int ks = 0; ks < 2; ++ks) {
        bf16x8 ap = ld_frag(&Ps[(wave*16 + fr)*VSTR + ks*32 + fo]);
        #pragma unroll
        for (int half = 0; half < 2; ++half) {
          bf16x8 bv[4];
          #pragma unroll
          for (int n = 0; n < 4; ++n)
            bv[n] = ld_frag(&Vs[((half*4 + n)*16 + fr)*64 + ((ks*4 + g) ^ (fr & 7))*8]);
          __builtin_amdgcn_s_setprio(1);
          #pragma unroll
          for (int n = 0; n < 4; ++n)
            oacc[half*4 + n] = MFMA_BF16(ap, bv[n], oacc[half*4 + n]);
          __builtin_amdgcn_s_setprio(0);
        }
      }
    }

    // epilogue: O over Q in-place; l lives in fr-space -> broadcast per O-row
    #pragma unroll
    for (int r = 0; r < 4; ++r) {
      float lr = __shfl(l_i, g*4 + r, 64);
      float inv_l = 1.0f / lr;
      #pragma unroll
      for (int n = 0; n < 8; ++n)
        Qh[(size_t)(orow_base + r)*HIDDEN + n*16 + fr] = f32_to_bf16(oacc[n][r] * inv_l);
    }
    __syncthreads();   // LDS/Q safe before next pass
  }
}

// ============================================================================
extern "C" void kernel_launch(void* const* d_in, const int* in_sizes, int n_in,
                              void* d_out, int out_size, void* d_ws, size_t ws_size,
                              hipStream_t stream)
{
  (void)in_sizes; (void)n_in; (void)out_size; (void)ws_size;
  const float* hidden = (const float*)d_in[0];   // fp32 per reference
  const float* wq = (const float*)d_in[2];
  const float* wk = (const float*)d_in[3];
  const float* wv = (const float*)d_in[4];
  const float* wo = (const float*)d_in[5];
  float* out = (float*)d_out;                    // fp32 per reference output

  // bf16 workspace with aliasing (~134 MB):
  //  R0: Xb (until qkv) -> Wob ; R1: Wqb (until qkv) -> Vt
  uint16_t* R0 = (uint16_t*)d_ws;                         // 16.78M elems
  uint16_t* R1 = R0 + (size_t)HIDDEN*HIDDEN;              // 16.78M
  uint16_t* R2 = R1 + (size_t)HIDDEN*HIDDEN;              //  4.19M
  uint16_t* R3 = R2 + (size_t)KVDIM*HIDDEN;               //  4.19M
  uint16_t* Qb = R3 + (size_t)KVDIM*HIDDEN;               // 16.78M
  uint16_t* Kb = Qb + (size_t)TOKENS*HIDDEN;              //  4.19M
  uint16_t* Vb = Kb + (size_t)TOKENS*KVDIM;               //  4.19M

  dim3 blk(256);
  cvt_all<<<dim3(20480), blk, 0, stream>>>(hidden, wq, wk, wv, R0, R1, R2, R3);
  qkv_gemm<<<dim3(48, TOKENS/128), blk, 0, stream>>>(R0, R1, R2, R3, Qb, Kb, Vb);
  rope_kernel<<<dim3(TOKENS*(NH+NKVH)*64/256), blk, 0, stream>>>(Qb, Kb);
  cvt_one<<<dim3(HIDDEN*HIDDEN/8/256), blk, 0, stream>>>(wo, R0);   // Wo -> R0 (Xb dead)
  transpose_v<<<dim3(SEQ/64, HD/64, BATCH*NKVH), blk, 0, stream>>>(Vb, R1); // Vt -> R1
  flash_attn<<<dim3(16, BATCH*NH), blk, 0, stream>>>(Qb, Kb, R1);
  out_gemm<<<dim3(HIDDEN/128, TOKENS/128), blk, 0, stream>>>(Qb, R0, out, HIDDEN, HIDDEN);
}